// Round 2
// baseline (36486.942 us; speedup 1.0000x reference)
//
#include <hip/hip_runtime.h>
#include <hip/hip_bf16.h>
#include <hip/hip_cooperative_groups.h>

namespace cg = cooperative_groups;

#define T_STEPS 512
#define BATCH   64
#define HID     1024
#define NLAYER  3
#define EPSV    1e-5f

typedef __attribute__((ext_vector_type(8))) short    short8;
typedef __attribute__((ext_vector_type(8))) _Float16 f16x8;
typedef __attribute__((ext_vector_type(4))) float    f32x4;

// packed activation layout within one [64 rows x 1024 k] fp16 buffer (65536 elems):
// [kc(8)][mt(4)][ki(4)][lane(64)][j(8)]  where row = mt*16 + (lane&15),
// k = kc*128 + ki*32 + (lane>>4)*8 + j
__device__ __forceinline__ int act_pack_idx(int row, int k) {
  int mt = row >> 4, lr = row & 15;
  int kc = k >> 7;
  int ki = (k >> 5) & 3;
  int lh = (k >> 3) & 3;
  int j  = k & 7;
  int lane = lr | (lh << 4);
  return ((((kc * 4 + mt) * 4 + ki) * 64) + lane) * 8 + j;
}

__device__ __forceinline__ float sigmoidf_(float v) {
  return 1.f / (1.f + __expf(-v));
}

__device__ __forceinline__ void reduce2(float& a, float& b, float* red) {
  #pragma unroll
  for (int o = 32; o; o >>= 1) {
    a += __shfl_xor(a, o, 64);
    b += __shfl_xor(b, o, 64);
  }
  int w = threadIdx.x >> 6;
  if ((threadIdx.x & 63) == 0) { red[w * 2] = a; red[w * 2 + 1] = b; }
  __syncthreads();
  a = red[0] + red[2] + red[4] + red[6];
  b = red[1] + red[3] + red[5] + red[7];
  __syncthreads();
}

// Wpack per layer: [ncb(64)][kc(16)][nt(4)][ki(4)][lane(64)][j(8)]
// n = ncb*64 + nt*16 + (lane&15); k = kc*128 + ki*32 + (lane>>4)*8 + j
// k<1024 -> Wx[n][k], else Wh[n][k-1024]
__global__ __launch_bounds__(256) void pack_weights(
    const float* __restrict__ Wx, const float* __restrict__ Wh,
    _Float16* __restrict__ Wpack) {
  long idx = (long)blockIdx.x * 256 + threadIdx.x;  // exactly 3*4096*2048 threads
  int l  = (int)(idx / 8388608);
  int r  = (int)(idx % 8388608);
  int ncb = r >> 17;
  int r2 = r & 131071;
  int kc = r2 >> 13;
  int r3 = r2 & 8191;
  int nt = r3 >> 11;
  int r4 = r3 & 2047;
  int ki = r4 >> 9;
  int r5 = r4 & 511;
  int lane = r5 >> 3, j = r5 & 7;
  int n = ncb * 64 + nt * 16 + (lane & 15);
  int k = kc * 128 + ki * 32 + ((lane >> 4) << 3) + j;
  float v = (k < 1024) ? Wx[((size_t)l * 4096 + n) * 1024 + k]
                       : Wh[((size_t)l * 4096 + n) * 1024 + (k - 1024)];
  Wpack[idx] = (_Float16)v;
}

// zero actsA[1..2] + actsB[0..2] (5*65536 halfwords, contiguous after actsA[0]),
// zero c_state, pack x[t=0] into actsA[0].
__global__ __launch_bounds__(256) void init_all(
    const float* __restrict__ x, _Float16* __restrict__ actsA,
    float* __restrict__ c_state) {
  int i = blockIdx.x * 256 + threadIdx.x;  // exactly 589824 threads
  if (i < 327680) {
    ((unsigned short*)(actsA + 65536))[i] = 0;
  } else if (i < 327680 + 196608) {
    c_state[i - 327680] = 0.f;
  } else {
    int q = i - (327680 + 196608);
    int b = q >> 10, e = q & 1023;
    actsA[act_pack_idx(b, e)] = (_Float16)x[(size_t)b * 1024 + e];
  }
}

__global__ __launch_bounds__(256) void lstm_main(
    const float* __restrict__ x, const float* __restrict__ bh,
    const float* __restrict__ ln_g, const float* __restrict__ ln_b,
    const float* __restrict__ lnc_g, const float* __restrict__ lnc_b,
    const _Float16* __restrict__ Wpack,
    _Float16* __restrict__ actsA, _Float16* __restrict__ actsB,
    float* __restrict__ ifgo, float* __restrict__ c_state,
    float* __restrict__ out_all) {
  cg::grid_group grid = cg::this_grid();
  __shared__ short lds[16384];   // [0..8192): W chunk, [8192..16384): acts chunk
  __shared__ float red[8];
  const int bid = blockIdx.x, tid = threadIdx.x;
  const int l = bid >> 6, sub = bid & 63;
  const int w = tid >> 6, lane = tid & 63;

  for (int s = 0; s < T_STEPS + NLAYER - 1; ++s) {
    const int t = s - l;
    const bool active = (t >= 0) && (t < T_STEPS);

    // ---------------- phase A: GEMM  ifgo[l] = acts @ W^T ----------------
    if (active) {
      const _Float16* A0 = actsA + l * 65536;  // input (x or h_{l-1}) packed
      const _Float16* B0 = actsB + l * 65536;  // own h packed
      const _Float16* Wl = Wpack + ((size_t)(l * 64 + sub)) * 131072;
      f32x4 acc[4];
      #pragma unroll
      for (int nt = 0; nt < 4; ++nt) acc[nt] = (f32x4){0.f, 0.f, 0.f, 0.f};

      for (int kc = 0; kc < 16; ++kc) {
        const _Float16* wsrc = Wl + kc * 8192;
        const _Float16* asrc = (kc < 8) ? (A0 + kc * 8192)
                                        : (B0 + (kc - 8) * 8192);
        __syncthreads();
        #pragma unroll
        for (int i = 0; i < 4; ++i) {
          const int o = (i * 256 + tid) * 8;
          *(short8*)(&lds[o])        = *(const short8*)(wsrc + o);
          *(short8*)(&lds[8192 + o]) = *(const short8*)(asrc + o);
        }
        __syncthreads();
        #pragma unroll
        for (int ki = 0; ki < 4; ++ki) {
          f16x8 a = *(const f16x8*)(&lds[8192 + ((w * 4 + ki) * 64 + lane) * 8]);
          #pragma unroll
          for (int nt = 0; nt < 4; ++nt) {
            f16x8 bb = *(const f16x8*)(&lds[((nt * 4 + ki) * 64 + lane) * 8]);
            acc[nt] = __builtin_amdgcn_mfma_f32_16x16x32_f16(a, bb, acc[nt], 0, 0, 0);
          }
        }
      }
      float* orow = ifgo + (size_t)l * BATCH * 4096;
      const int m0 = w * 16 + ((lane >> 4) << 2);
      const int nbase = sub * 64 + (lane & 15);
      #pragma unroll
      for (int nt = 0; nt < 4; ++nt)
        #pragma unroll
        for (int r = 0; r < 4; ++r)
          orow[(size_t)(m0 + r) * 4096 + nbase + nt * 16] = acc[nt][r];
    }
    grid.sync();

    // ---------------- phase B: LN gates + cell + LN(c) + h ----------------
    if (active) {
      const int b = sub;
      const float* row = ifgo + ((size_t)(l * BATCH + b)) * 4096;
      float v[4][4], actv[4][4];
      #pragma unroll
      for (int gi = 0; gi < 4; ++gi) {
        f32x4 rv = *(const f32x4*)(row + gi * 1024 + tid * 4);
        f32x4 bb = *(const f32x4*)(bh + l * 4096 + gi * 1024 + tid * 4);
        float s1 = 0.f, s2 = 0.f;
        #pragma unroll
        for (int j = 0; j < 4; ++j) {
          float vv = rv[j] + bb[j];
          v[gi][j] = vv; s1 += vv; s2 += vv * vv;
        }
        reduce2(s1, s2, red);
        float mu  = s1 * (1.f / 1024.f);
        float var = fmaxf(s2 * (1.f / 1024.f) - mu * mu, 0.f);
        float inv = rsqrtf(var + EPSV);
        #pragma unroll
        for (int j = 0; j < 4; ++j) {
          int e = tid * 4 + j;
          actv[gi][j] = (v[gi][j] - mu) * inv * ln_g[(l * 4 + gi) * 1024 + e]
                        + ln_b[(l * 4 + gi) * 1024 + e];
        }
      }
      float* crow = c_state + ((size_t)(l * BATCH + b)) * 1024;
      f32x4 cold = *(const f32x4*)(crow + tid * 4);
      float cn[4];
      float s1 = 0.f, s2 = 0.f;
      #pragma unroll
      for (int j = 0; j < 4; ++j) {
        float ii = sigmoidf_(actv[0][j]);
        float ff = sigmoidf_(actv[1][j]);
        float gg = tanhf(actv[2][j]);
        cn[j] = ff * cold[j] + ii * gg;
        s1 += cn[j]; s2 += cn[j] * cn[j];
      }
      *(f32x4*)(crow + tid * 4) = (f32x4){cn[0], cn[1], cn[2], cn[3]};
      reduce2(s1, s2, red);
      float mu  = s1 * (1.f / 1024.f);
      float var = fmaxf(s2 * (1.f / 1024.f) - mu * mu, 0.f);
      float inv = rsqrtf(var + EPSV);
      float hn[4];
      #pragma unroll
      for (int j = 0; j < 4; ++j) {
        int e = tid * 4 + j;
        float cl = (cn[j] - mu) * inv * lnc_g[l * 1024 + e] + lnc_b[l * 1024 + e];
        hn[j] = sigmoidf_(actv[3][j]) * tanhf(cl);
      }
      _Float16* selfB = actsB + l * 65536;
      #pragma unroll
      for (int j = 0; j < 4; ++j)
        selfB[act_pack_idx(b, tid * 4 + j)] = (_Float16)hn[j];
      if (l < 2) {
        _Float16* nxtA = actsA + (l + 1) * 65536;
        #pragma unroll
        for (int j = 0; j < 4; ++j)
          nxtA[act_pack_idx(b, tid * 4 + j)] = (_Float16)hn[j];
      } else {
        float* op = out_all + ((size_t)t * BATCH + b) * 1024 + tid * 4;
        *(f32x4*)op = (f32x4){hn[0], hn[1], hn[2], hn[3]};
      }
      if (t == T_STEPS - 1) {
        float* hsec = out_all + (size_t)T_STEPS * BATCH * 1024
                      + ((size_t)(l * BATCH + b)) * 1024 + tid * 4;
        float* csec = hsec + (size_t)NLAYER * BATCH * 1024;
        *(f32x4*)hsec = (f32x4){hn[0], hn[1], hn[2], hn[3]};
        *(f32x4*)csec = (f32x4){cn[0], cn[1], cn[2], cn[3]};
      }
    }
    // layer-0 blocks also pack x[s+1] for next step
    if (l == 0 && (s + 1) < T_STEPS) {
      const int b = sub;
      f32x4 xv = *(const f32x4*)(x + ((size_t)(s + 1) * BATCH + b) * 1024 + tid * 4);
      #pragma unroll
      for (int j = 0; j < 4; ++j)
        actsA[act_pack_idx(b, tid * 4 + j)] = (_Float16)xv[j];
    }
    grid.sync();
  }
}

extern "C" void kernel_launch(void* const* d_in, const int* in_sizes, int n_in,
                              void* d_out, int out_size, void* d_ws, size_t ws_size,
                              hipStream_t stream) {
  const float* x     = (const float*)d_in[0];
  const float* Wx    = (const float*)d_in[1];
  const float* Wh    = (const float*)d_in[2];
  const float* bh    = (const float*)d_in[3];
  const float* ln_g  = (const float*)d_in[4];
  const float* ln_b  = (const float*)d_in[5];
  const float* lnc_g = (const float*)d_in[6];
  const float* lnc_b = (const float*)d_in[7];

  char* ws = (char*)d_ws;
  _Float16* Wpack = (_Float16*)ws;                                          // 50331648 B
  _Float16* actsA = (_Float16*)(ws + 50331648);                             // 393216 B (3 x 65536)
  _Float16* actsB = (_Float16*)(ws + 50331648 + 393216);                    // 393216 B
  float* ifgo    = (float*)(ws + 50331648 + 786432);                        // 3145728 B
  float* c_state = (float*)(ws + 50331648 + 786432 + 3145728);              // 786432 B
  float* out_all = (float*)d_out;

  pack_weights<<<98304, 256, 0, stream>>>(Wx, Wh, Wpack);
  init_all<<<2304, 256, 0, stream>>>(x, actsA, c_state);

  void* args[] = { (void*)&x, (void*)&bh, (void*)&ln_g, (void*)&ln_b,
                   (void*)&lnc_g, (void*)&lnc_b, (void*)&Wpack, (void*)&actsA,
                   (void*)&actsB, (void*)&ifgo, (void*)&c_state, (void*)&out_all };
  hipLaunchCooperativeKernel((void*)lstm_main, dim3(192), dim3(256), args, 0, stream);
}